// Round 11
// baseline (40.414 us; speedup 1.0000x reference)
//
#include <hip/hip_runtime.h>
#include <stdint.h>

typedef unsigned long long u64;
typedef __attribute__((ext_vector_type(8))) short bf16x8;   // 8 bf16 (4 VGPRs)
typedef __attribute__((ext_vector_type(4))) float f32x4;    // MFMA acc

#define IN_FEATURES 256
#define UNITS 256
#define BM 64          // rows per block
#define LDK 264        // padded LDS stride in ushorts (528 B)

// sign(x) as bf16 bits: 0 for ±0, else ±1.0 (0x3F80 | signbit). Exact.
__device__ __forceinline__ ushort sgn_bf16(float f) {
    uint u = __float_as_uint(f);
    return ((u << 1) == 0u) ? (ushort)0 : (ushort)(0x3F80u | ((u >> 16) & 0x8000u));
}
__device__ __forceinline__ uint sgn_pack2(float a, float b) {
    return (uint)sgn_bf16(a) | ((uint)sgn_bf16(b) << 16);
}

// ---------------------------------------------------------------------------
// Pack kernel (verified R5): w -> sign-bf16 in MFMA fragment layout.
// Fragment (ks, ct, lane): col = ct*16 + (lane&15), k = ks*32 + (lane>>4)*8 .. +8
// fragB element index: ((ks*16 + ct)*64 + lane) * 8 ushorts.  Total 128 KB.
// ---------------------------------------------------------------------------
__global__ __launch_bounds__(256) void pack_w_frag(const float* __restrict__ w,
                                                   ushort* __restrict__ fragB) {
    __shared__ ushort ls[256][17];  // [k][c], +1 pad
    const int ct = blockIdx.x;      // col-tile 0..15
    const int t = threadIdx.x;

    const float4* wr = (const float4*)(w + (size_t)t * UNITS + ct * 16);
#pragma unroll
    for (int i = 0; i < 4; ++i) {
        const float4 v = wr[i];
        ls[t][i * 4 + 0] = sgn_bf16(v.x);
        ls[t][i * 4 + 1] = sgn_bf16(v.y);
        ls[t][i * 4 + 2] = sgn_bf16(v.z);
        ls[t][i * 4 + 3] = sgn_bf16(v.w);
    }
    __syncthreads();

#pragma unroll
    for (int h = 0; h < 2; ++h) {
        const int f = t + h * 256;
        const int ks = f >> 6;        // 0..7
        const int lane = f & 63;
        const int c = lane & 15;
        const int k0 = ks * 32 + (lane >> 4) * 8;
        alignas(16) ushort tmp[8];
#pragma unroll
        for (int j = 0; j < 8; ++j) tmp[j] = ls[k0 + j][c];
        *(uint4*)(fragB + ((size_t)(ks * 16 + ct) * 64 + lane) * 8) = *(const uint4*)tmp;
    }
}

// ---------------------------------------------------------------------------
// Main kernel = R5's verified bdense_mfma3 structure with 3 diffs:
//  (a) nontemporal C-stores  -> out bypasses L3, x stays L3-resident
//  (b) swapped-operand MFMA  -> transposed C fragment -> f32x4 stores
//      (verified absmax-0 in R6/R8/R10)
//  (c) staging in 2 register batches of 8 float4 (staging MLP 2 -> 8)
// ---------------------------------------------------------------------------
__global__ __launch_bounds__(256, 2) void bdense_v11(const float4* __restrict__ x4,
                                                     const ushort* __restrict__ fragB,
                                                     float* __restrict__ out) {
    __shared__ ushort xs[BM][LDK];  // 33792 B

    const int tid = threadIdx.x;
    const int lane = tid & 63;
    const int wid = tid >> 6;
    const long row0 = (long)blockIdx.x * BM;

    // --- stage: 64 rows x 256 k, batched (8 loads in flight per batch) ---
#pragma unroll
    for (int h = 0; h < 2; ++h) {
        float4 v[8];
#pragma unroll
        for (int i = 0; i < 8; ++i) {
            const int f = (h * 8 + i) * 256 + tid;
            v[i] = x4[(row0 + (f >> 6)) * (IN_FEATURES / 4) + (f & 63)];
        }
#pragma unroll
        for (int i = 0; i < 8; ++i) {
            const int f = (h * 8 + i) * 256 + tid;
            const int r = f >> 6;
            const int kq = f & 63;
            *(uint2*)&xs[r][kq * 4] =
                make_uint2(sgn_pack2(v[i].x, v[i].y), sgn_pack2(v[i].z, v[i].w));
        }
    }
    __syncthreads();

    f32x4 acc[4][4];
#pragma unroll
    for (int mt = 0; mt < 4; ++mt)
#pragma unroll
        for (int nt = 0; nt < 4; ++nt) acc[mt][nt] = (f32x4){0.f, 0.f, 0.f, 0.f};

    const int rl = lane & 15;
    const int klb = (lane >> 4) * 8;
    const int ct0 = wid * 4;  // this wave's first col-tile

#pragma unroll
    for (int ks = 0; ks < 8; ++ks) {
        const int kk = ks * 32 + klb;

        bf16x8 a[4], b[4];
#pragma unroll
        for (int mt = 0; mt < 4; ++mt)
            a[mt] = *(const bf16x8*)&xs[mt * 16 + rl][kk];        // ds_read_b128

        const ushort* bp = fragB + ((size_t)(ks * 16 + ct0) * 64 + lane) * 8;
#pragma unroll
        for (int nt = 0; nt < 4; ++nt)
            b[nt] = *(const bf16x8*)(bp + nt * 512);              // coalesced 1KB/wave

        // swapped operands: computes transposed C fragment (verified)
#pragma unroll
        for (int mt = 0; mt < 4; ++mt)
#pragma unroll
            for (int nt = 0; nt < 4; ++nt)
                acc[mt][nt] = __builtin_amdgcn_mfma_f32_16x16x32_bf16(
                    b[nt], a[mt], acc[mt][nt], 0, 0, 0);
    }

    // --- store: lane holds row rl, 4 consecutive cols at (lane>>4)*4 ---
    const int cl4 = (lane >> 4) * 4;
    const int colbase = wid * 64;
#pragma unroll
    for (int mt = 0; mt < 4; ++mt) {
        const long rowt = row0 + mt * 16 + rl;
#pragma unroll
        for (int nt = 0; nt < 4; ++nt) {
            f32x4* dst = (f32x4*)(out + rowt * UNITS + colbase + nt * 16 + cl4);
            __builtin_nontemporal_store(acc[mt][nt], dst);   // bypass L3
        }
    }
}

// ---------------------------------------------------------------------------
// Fallback (ws too small): round-2 popcount path, known-correct.
// ---------------------------------------------------------------------------
__global__ __launch_bounds__(256) void pack_w_bits(const float* __restrict__ w,
                                                   u64* __restrict__ wp) {
    const int t = blockIdx.x;
    const int j = threadIdx.x;
    u64 s = 0, z = 0;
#pragma unroll
    for (int b = 0; b < 64; ++b) {
        const float v = w[(4 * b + t) * UNITS + j];
        s |= ((u64)(v < 0.0f)) << b;
        z |= ((u64)(v != 0.0f)) << b;
    }
    wp[j * 4 + t] = s;
    wp[1024 + j * 4 + t] = z;
}

__global__ __launch_bounds__(256) void bdense_pop(const float4* __restrict__ x4,
                                                  const u64* __restrict__ wp,
                                                  float4* __restrict__ out4) {
    const int tid = threadIdx.x;
    const int lane = tid & 63;
    const int wid = tid >> 6;
    const long row0 = (long)blockIdx.x * 32 + (long)wid * 8;

    u64 ws_[4][4], wz_[4][4];
#pragma unroll
    for (int i = 0; i < 4; ++i)
#pragma unroll
        for (int t = 0; t < 4; ++t) {
            ws_[i][t] = wp[(4 * lane + i) * 4 + t];
            wz_[i][t] = wp[1024 + (4 * lane + i) * 4 + t];
        }

#pragma unroll
    for (int r = 0; r < 8; ++r) {
        const float4 v = x4[(row0 + r) * (IN_FEATURES / 4) + lane];
        u64 rs[4], rz[4];
        rs[0] = __ballot(v.x < 0.0f); rz[0] = __ballot(v.x != 0.0f);
        rs[1] = __ballot(v.y < 0.0f); rz[1] = __ballot(v.y != 0.0f);
        rs[2] = __ballot(v.z < 0.0f); rz[2] = __ballot(v.z != 0.0f);
        rs[3] = __ballot(v.w < 0.0f); rz[3] = __ballot(v.w != 0.0f);
        float o[4];
#pragma unroll
        for (int i = 0; i < 4; ++i) {
            int nzc = 0, ngc = 0;
#pragma unroll
            for (int t = 0; t < 4; ++t) {
                const u64 nz = rz[t] & wz_[i][t];
                const u64 d = (rs[t] ^ ws_[i][t]) & nz;
                nzc += __popcll(nz);
                ngc += __popcll(d);
            }
            o[i] = (float)(nzc - 2 * ngc);
        }
        out4[(row0 + r) * (UNITS / 4) + lane] = make_float4(o[0], o[1], o[2], o[3]);
    }
}

extern "C" void kernel_launch(void* const* d_in, const int* in_sizes, int n_in,
                              void* d_out, int out_size, void* d_ws, size_t ws_size,
                              hipStream_t stream) {
    const float* x = (const float*)d_in[0];
    const float* w = (const float*)d_in[1];
    float* out = (float*)d_out;

    const int batch = in_sizes[0] / IN_FEATURES;  // 65536

    if (ws_size >= (size_t)UNITS * IN_FEATURES * sizeof(ushort) && batch % BM == 0) {
        ushort* fragB = (ushort*)d_ws;
        pack_w_frag<<<16, 256, 0, stream>>>(w, fragB);
        bdense_v11<<<batch / BM, 256, 0, stream>>>((const float4*)x, fragB, out);
    } else {
        u64* wp = (u64*)d_ws;  // 16 KB
        pack_w_bits<<<4, 256, 0, stream>>>(w, wp);
        bdense_pop<<<batch / 32, 256, 0, stream>>>((const float4*)x, wp, (float4*)out);
    }
}